// Round 8
// baseline (418.893 us; speedup 1.0000x reference)
//
#include <hip/hip_runtime.h>
#include <hip/hip_bf16.h>
#include <math.h>

#define B_DIM 8
#define S_DIM 4096
#define DIN   1024
#define DHID  1024
#define DOUT  1024
#define LDA   1024          // all GEMM operands are [*][1024] after PE-fold
#define MTOT  (B_DIM*S_DIM) // 32768
#define NCHUNK 32
#define LCHUNK 128

typedef __attribute__((ext_vector_type(8))) short bf16x8;
typedef __attribute__((ext_vector_type(4))) float f32x4;
typedef __attribute__((ext_vector_type(4))) unsigned short u16x4;
typedef __attribute__((ext_vector_type(8))) unsigned short u16x8;

__device__ __forceinline__ unsigned short f2bf(float f) {
  union { float f; unsigned u; } v; v.f = f;
  unsigned r = v.u + 0x7fffu + ((v.u >> 16) & 1u);
  return (unsigned short)(r >> 16);
}
__device__ __forceinline__ float bf2f(unsigned short h) {
  union { unsigned u; float f; } v; v.u = ((unsigned)h) << 16;
  return v.f;
}

// async global->LDS, 16B per lane; LDS dest = wave-uniform base + lane*16
#define GLOAD16(g, l)                                                         \
  __builtin_amdgcn_global_load_lds(                                           \
      (const __attribute__((address_space(1))) void*)(g),                     \
      (__attribute__((address_space(3))) void*)(l), 16, 0, 0)

#define BAR()   __builtin_amdgcn_s_barrier()
#define SCHED0() __builtin_amdgcn_sched_barrier(0)
#define LGKM0() do { asm volatile("s_waitcnt lgkmcnt(0)" ::: "memory");       \
                     __builtin_amdgcn_sched_barrier(0); } while (0)

// ---------------- prep kernels ----------------

__global__ void prep_a_kernel(const float* __restrict__ logit,
                              float* __restrict__ avec, float* __restrict__ svec) {
  int d = blockIdx.x * 256 + threadIdx.x;
  if (d >= DHID) return;
  float a = 1.f / (1.f + expf(-logit[d]));
  avec[d] = a;
  svec[d] = sqrtf(fmaxf(0.f, 1.f - a * a));
}

// W[K][1024] fp32 -> Wt[1024][1024] bf16 (first 1024 K-rows only)
__global__ __launch_bounds__(256) void transpose_cast_kernel(
    const float* __restrict__ W, unsigned short* __restrict__ Wt) {
  __shared__ float tile[32][33];
  const int N = 1024;
  int kb = blockIdx.x * 32, nb = blockIdx.y * 32;
  int tx = threadIdx.x & 31, ty = threadIdx.x >> 5;  // ty 0..7
#pragma unroll
  for (int r = 0; r < 32; r += 8)
    tile[ty + r][tx] = W[(size_t)(kb + ty + r) * N + nb + tx];
  __syncthreads();
#pragma unroll
  for (int r = 0; r < 32; r += 8)
    Wt[(size_t)(nb + ty + r) * N + kb + tx] = f2bf(tile[tx][ty + r]);
}

// PEB[t][col] = sum_j pe(t,j)*W[1024+j][col] + ba[col] + sb*bb[col]
__global__ __launch_bounds__(256) void pew_kernel(const float* __restrict__ W,
                                                  const float* __restrict__ ba,
                                                  const float* __restrict__ bb,
                                                  float sb,
                                                  float* __restrict__ PEB) {
  __shared__ float pe[16];
  int t = blockIdx.x;
  if (threadIdx.x < 16) {
    int j = threadIdx.x, i = j >> 1;
    float div = expf(-(float)i * 1.1512925465f);  // 10000^(-i/8)
    float arg = (float)t * div;
    pe[j] = (j & 1) ? cosf(arg) : sinf(arg);
  }
  __syncthreads();
  int col0 = threadIdx.x * 4;
  float4 bav = *(const float4*)(ba + col0);
  float4 bbv = *(const float4*)(bb + col0);
  float a0 = bav.x + sb * bbv.x, a1 = bav.y + sb * bbv.y;
  float a2 = bav.z + sb * bbv.z, a3 = bav.w + sb * bbv.w;
#pragma unroll
  for (int j = 0; j < 16; j++) {
    const float4 wv = *(const float4*)(W + (size_t)(1024 + j) * 1024 + col0);
    float p = pe[j];
    a0 = fmaf(p, wv.x, a0); a1 = fmaf(p, wv.y, a1);
    a2 = fmaf(p, wv.z, a2); a3 = fmaf(p, wv.w, a3);
  }
  float4 o = {a0, a1, a2, a3};
  *(float4*)(PEB + (size_t)t * 1024 + col0) = o;
}

// x fp32 -> bf16 (pure streaming cast, 8 elems/thread)
__global__ __launch_bounds__(256) void cast_kernel(const float* __restrict__ x,
                                                   unsigned short* __restrict__ xb) {
  size_t i = ((size_t)blockIdx.x * 256 + threadIdx.x) * 8;  // grid covers exactly
  float4 v0 = *(const float4*)(x + i);
  float4 v1 = *(const float4*)(x + i + 4);
  u16x8 o;
  o[0] = f2bf(v0.x); o[1] = f2bf(v0.y); o[2] = f2bf(v0.z); o[3] = f2bf(v0.w);
  o[4] = f2bf(v1.x); o[5] = f2bf(v1.y); o[6] = f2bf(v1.z); o[7] = f2bf(v1.w);
  *(u16x8*)(xb + i) = o;
}

// ===== gemm_out: R3-verbatim 256x256 pipe (BK=64, 4 phases, bunched staging) =====
// Half-tile = [128 rows][64 K] bf16 = 16KB, chunk = 16B: c = row*8 + slot.
// Swizzle: phys_slot = slot ^ (row&7); linear LDS dest, pre-swizzled global source.

__device__ __forceinline__ bf16x8 frag64(const unsigned short* hb, int row, int slot) {
  int ph = slot ^ (row & 7);
  return *(const bf16x8*)(hb + (size_t)row * 64 + ph * 8);
}

#define READ_A4(dst, base, roff)                                              \
  _Pragma("unroll") for (int mq = 0; mq < 4; mq++)                            \
    _Pragma("unroll") for (int kk = 0; kk < 2; kk++)                          \
      dst[mq][kk] = frag64(base, (roff) + mq * 16 + rl, kk * 4 + s);

#define READ_B2(dst, base, roff)                                              \
  _Pragma("unroll") for (int nq = 0; nq < 2; nq++)                            \
    _Pragma("unroll") for (int kk = 0; kk < 2; kk++)                          \
      dst[nq][kk] = frag64(base, (roff) + nq * 16 + rl, kk * 4 + s);

#define MFMA_Q(MH, NH, BB)                                                    \
  __builtin_amdgcn_s_setprio(1);                                              \
  _Pragma("unroll") for (int mq = 0; mq < 4; mq++)                            \
    _Pragma("unroll") for (int nq = 0; nq < 2; nq++)                          \
      _Pragma("unroll") for (int kk = 0; kk < 2; kk++)                        \
        acc[(MH)*4 + mq][(NH)*2 + nq] =                                       \
            __builtin_amdgcn_mfma_f32_16x16x32_bf16(                          \
                a[mq][kk], BB[nq][kk], acc[(MH)*4 + mq][(NH)*2 + nq], 0,0,0); \
  __builtin_amdgcn_s_setprio(0);

__device__ __forceinline__ void gemm_pipe2(
    const unsigned short* __restrict__ A,   // [M][1024] bf16 row-major
    const unsigned short* __restrict__ Bt,  // [N][1024] bf16 row-major (B^T)
    int kt, int arow0, int brow0,
    unsigned short (*lA)[2][8192], unsigned short (*lB)[2][8192],
    f32x4 acc[8][4]) {
  const int tid = threadIdx.x;
  const int lane = tid & 63, w = tid >> 6;
  const int wrow = w >> 2, wcol = w & 3;   // 2M x 4N wave grid, per-wave 128x64
  const int rl = lane & 15, s = lane >> 4;

  const int c1 = tid, c2 = tid + 512;
  const int r1 = c1 >> 3, sl1 = (c1 & 7) ^ (r1 & 7);
  const int r2 = c2 >> 3, sl2 = (c2 & 7) ^ (r2 & 7);
  const unsigned short* pA1 = A + (size_t)(arow0 + r1) * LDA + sl1 * 8;
  const unsigned short* pA2 = A + (size_t)(arow0 + r2) * LDA + sl2 * 8;
  const unsigned short* pB1 = Bt + (size_t)(brow0 + r1) * LDA + sl1 * 8;
  const unsigned short* pB2 = Bt + (size_t)(brow0 + r2) * LDA + sl2 * 8;
  const size_t hstep = (size_t)128 * LDA;

#define STG_A(t, h) do { size_t _o = (size_t)(t) * 64 + (size_t)(h) * hstep;  \
    int _b = (t) & 1;                                                         \
    GLOAD16(pA1 + _o, &lA[_b][h][(size_t)c1 * 8]);                            \
    GLOAD16(pA2 + _o, &lA[_b][h][(size_t)c2 * 8]); } while (0)
#define STG_B(t, h) do { size_t _o = (size_t)(t) * 64 + (size_t)(h) * hstep;  \
    int _b = (t) & 1;                                                         \
    GLOAD16(pB1 + _o, &lB[_b][h][(size_t)c1 * 8]);                            \
    GLOAD16(pB2 + _o, &lB[_b][h][(size_t)c2 * 8]); } while (0)

  // prologue: stage tiles 0 and 1
  STG_B(0, 0); STG_B(0, 1); STG_A(0, 0); STG_A(0, 1);
  STG_B(1, 0); STG_B(1, 1); STG_A(1, 0); STG_A(1, 1);
  asm volatile("s_waitcnt vmcnt(8)" ::: "memory");   // tile 0 landed
  BAR();

  const int br = (wcol & 1) * 64;
  for (int t = 0; t < kt; ++t) {
    const bool st = (t + 2) < kt;
    const unsigned short* Ac = &lA[t & 1][wrow][0];
    const unsigned short* Bc = &lB[t & 1][wcol >> 1][0];
    bf16x8 a[4][2], b0[2][2], b1[2][2];

    // P0: read A-lo + B-lo; MFMA Q(0,0)
    READ_A4(a, Ac, 0);
    READ_B2(b0, Bc, br);
    BAR(); LGKM0();
    MFMA_Q(0, 0, b0);
    BAR();

    // P1: read B-hi; MFMA Q(0,1)
    READ_B2(b1, Bc, br + 32);
    BAR(); LGKM0();
    MFMA_Q(0, 1, b1);
    BAR();

    // P2: read A-hi; stage B halves of t+2; MFMA Q(1,1)
    READ_A4(a, Ac, 64);
    if (st) { STG_B(t + 2, 0); STG_B(t + 2, 1); }
    BAR(); LGKM0();
    MFMA_Q(1, 1, b1);
    BAR();

    // P3: stage A halves of t+2; MFMA Q(1,0); counted vmcnt
    if (st) { STG_A(t + 2, 0); STG_A(t + 2, 1); }
    BAR();
    MFMA_Q(1, 0, b0);
    if (st) { asm volatile("s_waitcnt vmcnt(8)" ::: "memory"); }
    else    { asm volatile("s_waitcnt vmcnt(0)" ::: "memory"); }
    BAR();
  }
#undef STG_A
#undef STG_B
}

// out = 0.5f*(xb@Wdx' + h@Wout' + PEBdx[t])   (two 16-tile segments, R3 style)
__global__ __launch_bounds__(512, 2) void gemm_out_kernel(
    const unsigned short* __restrict__ xb, const unsigned short* __restrict__ Wtdx,
    const unsigned short* __restrict__ h, const unsigned short* __restrict__ Wtout,
    const float* __restrict__ PEBdx, float* __restrict__ out) {
  __shared__ __align__(16) unsigned short lA[2][2][8192];
  __shared__ __align__(16) unsigned short lB[2][2][8192];
  f32x4 acc[8][4];
  const f32x4 z = {0.f, 0.f, 0.f, 0.f};
#pragma unroll
  for (int i = 0; i < 8; i++)
#pragma unroll
    for (int n = 0; n < 4; n++) acc[i][n] = z;

  int bid = blockIdx.x;
  int swz = (bid & 7) * 64 + (bid >> 3);   // 512 % 8 == 0: bijective
  int bcol = swz >> 7, brow = swz & 127;

  gemm_pipe2(xb, Wtdx, LDA / 64, brow * 256, bcol * 256, lA, lB, acc);
  gemm_pipe2(h, Wtout, LDA / 64, brow * 256, bcol * 256, lA, lB, acc);

  const int lane = threadIdx.x & 63, w = threadIdx.x >> 6;
  const int wrow = w >> 2, wcol = w & 3;
  const int rl = lane & 15, s = lane >> 4;
  const int colb = bcol * 256 + wcol * 64 + rl;
  const int rowb = brow * 256 + wrow * 128 + s * 4;
#pragma unroll
  for (int n = 0; n < 4; n++) {
    int col = colb + n * 16;
#pragma unroll
    for (int i = 0; i < 8; i++) {
#pragma unroll
      for (int r = 0; r < 4; r++) {
        int row = rowb + i * 16 + r;
        float peb = PEBdx[(size_t)((row & (S_DIM - 1)) << 10) + col];
        out[(size_t)row * DOUT + col] = 0.5f * (acc[i][n][r] + peb);
      }
    }
  }
}

// ===== gemm_u EXPERIMENT: 16 waves (4x4 of 64x64), BK=32, 3-buffer, vmcnt(2) =====
// A/B tile = [256 rows][32 K] bf16 = 16KB/buf; 3 bufs x 2 operands = 96KB LDS.
// Chunk = 16B: c = row*4 + slot; swizzle phys_slot = slot ^ ((row>>1)&3).

__device__ __forceinline__ bf16x8 frag32(const unsigned short* hb, int row, int s) {
  int ph = s ^ ((row >> 1) & 3);
  return *(const bf16x8*)(hb + (size_t)row * 32 + ph * 8);
}

__global__ __launch_bounds__(1024) void gemm_u_kernel(
    const unsigned short* __restrict__ xb, const unsigned short* __restrict__ Wtin,
    const float* __restrict__ svec, const float* __restrict__ PEBin,
    unsigned short* __restrict__ u) {
  __shared__ __align__(16) unsigned short lA[3][8192];
  __shared__ __align__(16) unsigned short lB[3][8192];
  f32x4 acc[4][4];
  const f32x4 z = {0.f, 0.f, 0.f, 0.f};
#pragma unroll
  for (int m = 0; m < 4; m++)
#pragma unroll
    for (int n = 0; n < 4; n++) acc[m][n] = z;

  int bid = blockIdx.x;
  int swz = (bid & 7) * 64 + (bid >> 3);   // 512 % 8 == 0: bijective
  int bcol = swz >> 7, brow = swz & 127;

  const int tid = threadIdx.x;
  const int lane = tid & 63, w = tid >> 6;     // 16 waves
  const int wr = w >> 2, wc = w & 3;           // 4M x 4N grid, per-wave 64x64
  const int rl = lane & 15, s = lane >> 4;

  // staging: thread covers chunk tid (row tid>>2, slot tid&3) of each tile
  const int r1 = tid >> 2;
  const int sl1 = (tid & 3) ^ ((r1 >> 1) & 3);
  const unsigned short* gA = xb   + (size_t)(brow * 256 + r1) * LDA + sl1 * 8;
  const unsigned short* gB = Wtin + (size_t)(bcol * 256 + r1) * LDA + sl1 * 8;

  const int kt = LDA / 32;  // 32 tiles
  auto stage = [&](int t) {
    int b = t % 3;
    GLOAD16(gA + (size_t)t * 32, &lA[b][(size_t)tid * 8]);
    GLOAD16(gB + (size_t)t * 32, &lB[b][(size_t)tid * 8]);
  };

  stage(0); stage(1);
  asm volatile("s_waitcnt vmcnt(2)" ::: "memory");   // tile 0 landed
  BAR(); SCHED0();

  for (int t = 0; t < kt; ++t) {
    const bool st = (t + 2) < kt;
    if (st) stage(t + 2);
    const unsigned short* Ac = lA[t % 3];
    const unsigned short* Bc = lB[t % 3];
    bf16x8 af[4], bf[4];
#pragma unroll
    for (int m = 0; m < 4; m++) af[m] = frag32(Ac, wr * 64 + m * 16 + rl, s);
#pragma unroll
    for (int n = 0; n < 4; n++) bf[n] = frag32(Bc, wc * 64 + n * 16 + rl, s);
    __builtin_amdgcn_s_setprio(1);
#pragma unroll
    for (int m = 0; m < 4; m++)
#pragma unroll
      for (int n = 0; n < 4; n++)
        acc[m][n] = __builtin_amdgcn_mfma_f32_16x16x32_bf16(af[m], bf[n], acc[m][n], 0, 0, 0);
    __builtin_amdgcn_s_setprio(0);
    if (st) asm volatile("s_waitcnt vmcnt(2)" ::: "memory");  // tile t+1 landed
    else    asm volatile("s_waitcnt vmcnt(0)" ::: "memory");
    BAR(); SCHED0();
  }

  const int colb = bcol * 256 + wc * 64 + rl;
  const int rowb = brow * 256 + wr * 64 + s * 4;
#pragma unroll
  for (int n = 0; n < 4; n++) {
    int col = colb + n * 16;
    float sv = svec[col];
#pragma unroll
    for (int m = 0; m < 4; m++) {
#pragma unroll
      for (int r = 0; r < 4; r++) {
        int row = rowb + m * 16 + r;
        float peb = PEBin[(size_t)((row & (S_DIM - 1)) << 10) + col];
        u[(size_t)row * DHID + col] = f2bf((acc[m][n][r] + peb) * sv);
      }
    }
  }
}

// ---------------- chunked scan: h_t = a h_{t-1} + u_t ----------------

__global__ __launch_bounds__(256) void scan1_kernel(
    const float* __restrict__ avec, unsigned short* __restrict__ uh,
    float* __restrict__ carry) {
  int b = blockIdx.x >> 5, c = blockIdx.x & 31;
  int d0 = threadIdx.x * 4;
  float4 a4 = *(const float4*)(avec + d0);
  unsigned short* p = uh + ((size_t)(b * S_DIM + c * LCHUNK)) * DHID + d0;
  float h0 = 0.f, h1 = 0.f, h2 = 0.f, h3 = 0.f;
#pragma unroll 4
  for (int t = 0; t < LCHUNK; t++) {
    u16x4 v = *(u16x4*)(p + (size_t)t * DHID);
    h0 = fmaf(a4.x, h0, bf2f(v.x));
    h1 = fmaf(a4.y, h1, bf2f(v.y));
    h2 = fmaf(a4.z, h2, bf2f(v.z));
    h3 = fmaf(a4.w, h3, bf2f(v.w));
    v.x = f2bf(h0); v.y = f2bf(h1); v.z = f2bf(h2); v.w = f2bf(h3);
    *(u16x4*)(p + (size_t)t * DHID) = v;
  }
  float4 cv = {h0, h1, h2, h3};
  *(float4*)(carry + ((size_t)b * NCHUNK + c) * DHID + d0) = cv;
}

__global__ __launch_bounds__(256) void scan2_kernel(
    const float* __restrict__ avec, const float* __restrict__ carry,
    float* __restrict__ Hprev) {
  int gid = blockIdx.x * 256 + threadIdx.x;  // 0..8191
  int b = gid >> 10, d = gid & 1023;
  float a = avec[d];
  float aL = a;
#pragma unroll
  for (int i = 0; i < 7; i++) aL *= aL;  // a^128
  float H = 0.f;
#pragma unroll
  for (int c = 0; c < NCHUNK; c++) {
    size_t idx = ((size_t)b * NCHUNK + c) * DHID + d;
    Hprev[idx] = H;
    H = aL * H + carry[idx];
  }
}

__global__ __launch_bounds__(256) void scan3_kernel(
    const float* __restrict__ avec, unsigned short* __restrict__ uh,
    const float* __restrict__ Hprev) {
  int b = blockIdx.x >> 5, c = blockIdx.x & 31;
  int d0 = threadIdx.x * 4;
  float4 Hp = *(const float4*)(Hprev + ((size_t)b * NCHUNK + c) * DHID + d0);
  if (Hp.x == 0.f && Hp.y == 0.f && Hp.z == 0.f && Hp.w == 0.f) return;  // c==0
  float4 a4 = *(const float4*)(avec + d0);
  float p0 = a4.x * Hp.x, p1 = a4.y * Hp.y, p2 = a4.z * Hp.z, p3 = a4.w * Hp.w;
  unsigned short* p = uh + ((size_t)(b * S_DIM + c * LCHUNK)) * DHID + d0;
#pragma unroll 4
  for (int t = 0; t < LCHUNK; t++) {
    u16x4 v = *(u16x4*)(p + (size_t)t * DHID);
    v.x = f2bf(bf2f(v.x) + p0);
    v.y = f2bf(bf2f(v.y) + p1);
    v.z = f2bf(bf2f(v.z) + p2);
    v.w = f2bf(bf2f(v.w) + p3);
    *(u16x4*)(p + (size_t)t * DHID) = v;
    p0 *= a4.x; p1 *= a4.y; p2 *= a4.z; p3 *= a4.w;
  }
}

// ---------------- launch ----------------

extern "C" void kernel_launch(void* const* d_in, const int* in_sizes, int n_in,
                              void* d_out, int out_size, void* d_ws, size_t ws_size,
                              hipStream_t stream) {
  const float* x       = (const float*)d_in[0];
  const float* a_logit = (const float*)d_in[1];
  const float* W_dx    = (const float*)d_in[2];
  const float* b_dx    = (const float*)d_in[3];
  const float* W_in    = (const float*)d_in[4];
  const float* b_in    = (const float*)d_in[5];
  const float* W_out   = (const float*)d_in[6];
  const float* b_out   = (const float*)d_in[7];
  float* out = (float*)d_out;

  char* ws = (char*)d_ws;
  size_t off = 0;
  auto alloc = [&](size_t bytes) {
    void* p = ws + off;
    off += (bytes + 255) & ~(size_t)255;
    return p;
  };
  unsigned short* xb    = (unsigned short*)alloc((size_t)MTOT * 1024 * 2);
  unsigned short* Wtdx  = (unsigned short*)alloc((size_t)1024 * 1024 * 2);
  unsigned short* Wtin  = (unsigned short*)alloc((size_t)1024 * 1024 * 2);
  unsigned short* Wtout = (unsigned short*)alloc((size_t)1024 * 1024 * 2);
  unsigned short* uh    = (unsigned short*)alloc((size_t)MTOT * 1024 * 2);
  float* PEBdx = (float*)alloc((size_t)S_DIM * 1024 * 4);
  float* PEBin = (float*)alloc((size_t)S_DIM * 1024 * 4);
  float* carry = (float*)alloc((size_t)B_DIM * NCHUNK * DHID * 4);
  float* Hprev = (float*)alloc((size_t)B_DIM * NCHUNK * DHID * 4);
  float* avec  = (float*)alloc(DHID * 4);
  float* svec  = (float*)alloc(DHID * 4);
  (void)ws_size; (void)in_sizes; (void)n_in; (void)out_size;

  prep_a_kernel<<<4, 256, 0, stream>>>(a_logit, avec, svec);
  transpose_cast_kernel<<<dim3(32, 32), 256, 0, stream>>>(W_dx, Wtdx);
  transpose_cast_kernel<<<dim3(32, 32), 256, 0, stream>>>(W_in, Wtin);
  transpose_cast_kernel<<<dim3(32, 32), 256, 0, stream>>>(W_out, Wtout);
  pew_kernel<<<S_DIM, 256, 0, stream>>>(W_dx, b_dx, b_out, 1.0f, PEBdx);
  pew_kernel<<<S_DIM, 256, 0, stream>>>(W_in, b_in, b_in, 0.0f, PEBin);
  cast_kernel<<<MTOT * 1024 / 8 / 256, 256, 0, stream>>>(x, xb);

  gemm_u_kernel<<<512, 1024, 0, stream>>>(xb, Wtin, svec, PEBin, uh);

  scan1_kernel<<<B_DIM * NCHUNK, 256, 0, stream>>>(avec, uh, carry);
  scan2_kernel<<<32, 256, 0, stream>>>(avec, carry, Hprev);
  scan3_kernel<<<B_DIM * NCHUNK, 256, 0, stream>>>(avec, uh, Hprev);

  gemm_out_kernel<<<512, 512, 0, stream>>>(xb, Wtdx, uh, Wtout, PEBdx, out);
}

// Round 9
// 358.886 us; speedup vs baseline: 1.1672x; 1.1672x over previous
//
#include <hip/hip_runtime.h>
#include <hip/hip_bf16.h>
#include <math.h>

#define B_DIM 8
#define S_DIM 4096
#define DIN   1024
#define DHID  1024
#define DOUT  1024
#define KCAT  1040          // d_in + pe
#define KC    1088          // padded to %64==0 (17 K-tiles of 64)
#define MTOT  (B_DIM*S_DIM) // 32768
#define NCHUNK 32
#define LCHUNK 128

typedef __attribute__((ext_vector_type(8))) short bf16x8;
typedef __attribute__((ext_vector_type(4))) float f32x4;
typedef __attribute__((ext_vector_type(4))) unsigned short u16x4;

__device__ __forceinline__ unsigned short f2bf(float f) {
  union { float f; unsigned u; } v; v.f = f;
  unsigned r = v.u + 0x7fffu + ((v.u >> 16) & 1u);
  return (unsigned short)(r >> 16);
}
__device__ __forceinline__ float bf2f(unsigned short h) {
  union { unsigned u; float f; } v; v.u = ((unsigned)h) << 16;
  return v.f;
}

// async global->LDS, 16B per lane; LDS dest = wave-uniform base + lane*16
#define GLOAD16(g, l)                                                         \
  __builtin_amdgcn_global_load_lds(                                           \
      (const __attribute__((address_space(1))) void*)(g),                     \
      (__attribute__((address_space(3))) void*)(l), 16, 0, 0)

#define BAR()   __builtin_amdgcn_s_barrier()
#define LGKM0() do { asm volatile("s_waitcnt lgkmcnt(0)" ::: "memory");       \
                     __builtin_amdgcn_sched_barrier(0); } while (0)

// ---------------- prep kernels ----------------

__global__ void prep_a_kernel(const float* __restrict__ logit,
                              float* __restrict__ avec, float* __restrict__ svec) {
  int d = blockIdx.x * 256 + threadIdx.x;
  if (d >= DHID) return;
  float a = 1.f / (1.f + expf(-logit[d]));
  avec[d] = a;
  svec[d] = sqrtf(fmaxf(0.f, 1.f - a * a));
}

// W[K][N] fp32 -> Wt[N][KCdst] bf16 (zero-pad k >= Ksrc)
__global__ __launch_bounds__(256) void transpose_cast_kernel(
    const float* __restrict__ W, unsigned short* __restrict__ Wt,
    int Ksrc, int KCdst) {
  __shared__ float tile[32][33];
  const int N = 1024;
  int kb = blockIdx.x * 32, nb = blockIdx.y * 32;
  int tx = threadIdx.x & 31, ty = threadIdx.x >> 5;  // ty 0..7
#pragma unroll
  for (int r = 0; r < 32; r += 8) {
    int k = kb + ty + r;
    tile[ty + r][tx] = (k < Ksrc) ? W[(size_t)k * N + nb + tx] : 0.f;
  }
  __syncthreads();
#pragma unroll
  for (int r = 0; r < 32; r += 8) {
    int n = nb + ty + r;
    Wt[(size_t)n * KCdst + kb + tx] = f2bf(tile[tx][ty + r]);
  }
}

// xc[row][0..1023]=x, [1024..1039]=PE(t), [1040..1087]=0   (bf16)
__global__ __launch_bounds__(256) void build_xc_kernel(
    const float* __restrict__ x, unsigned short* __restrict__ xc) {
  int gid = blockIdx.x * 256 + threadIdx.x;  // over MTOT * (KC/4)
  if (gid >= MTOT * (KC / 4)) return;
  int row = gid / (KC / 4);
  int g = gid - row * (KC / 4);
  int col0 = g * 4;
  u16x4 val;
  if (col0 < DIN) {
    const float4 xv = *(const float4*)(x + (size_t)row * DIN + col0);
    val.x = f2bf(xv.x); val.y = f2bf(xv.y); val.z = f2bf(xv.z); val.w = f2bf(xv.w);
  } else {
    int t = row & (S_DIM - 1);
#pragma unroll
    for (int e = 0; e < 4; e++) {
      int col = col0 + e;
      float v = 0.f;
      if (col < KCAT) {
        int j = col - DIN;
        int i = j >> 1;
        float div = expf(-(float)i * 1.1512925465f);  // 10000^(-i/8)
        float arg = (float)t * div;
        v = (j & 1) ? cosf(arg) : sinf(arg);
      }
      val[e] = f2bf(v);
    }
  }
  *(u16x4*)(xc + (size_t)row * KC + col0) = val;
}

// ------- 256x256 GEMM, BK=64, 4 phases/tile, m201 staging discipline -------
// Half-tile = [128 rows][64 K] bf16 = 16KB, chunk = 16B: c = row*8 + slot.
// Swizzle: phys_slot = slot ^ (row&7); linear LDS dest, pre-swizzled global source.
// Staging: ONE 2-load quarter-unit per phase: P0: A-upper(t+1), P1: A-lower(t+2),
// P2: B-lower(t+2), P3: B-upper(t+2). Single vmcnt(6) per tile at P3 end — the
// newest load it waits on (A-upper(t+1)) was issued 4 phases earlier.
// Race-free: each staged region's consuming lgkmcnt(0) is >=1 barrier earlier.

__device__ __forceinline__ bf16x8 frag(const unsigned short* hb, int row, int slot) {
  int ph = slot ^ (row & 7);
  return *(const bf16x8*)(hb + (size_t)row * 64 + ph * 8);
}

#define READ_A4(dst, base, roff)                                              \
  _Pragma("unroll") for (int mq = 0; mq < 4; mq++)                            \
    _Pragma("unroll") for (int kk = 0; kk < 2; kk++)                          \
      dst[mq][kk] = frag(base, (roff) + mq * 16 + rl, kk * 4 + s);

#define READ_B2(dst, base, roff)                                              \
  _Pragma("unroll") for (int nq = 0; nq < 2; nq++)                            \
    _Pragma("unroll") for (int kk = 0; kk < 2; kk++)                          \
      dst[nq][kk] = frag(base, (roff) + nq * 16 + rl, kk * 4 + s);

#define MFMA_Q(MH, NH, AA, BB)                                                \
  __builtin_amdgcn_s_setprio(1);                                              \
  _Pragma("unroll") for (int mq = 0; mq < 4; mq++)                            \
    _Pragma("unroll") for (int nq = 0; nq < 2; nq++)                          \
      _Pragma("unroll") for (int kk = 0; kk < 2; kk++)                        \
        acc[(MH)*4 + mq][(NH)*2 + nq] =                                       \
            __builtin_amdgcn_mfma_f32_16x16x32_bf16(                          \
                AA[mq][kk], BB[nq][kk], acc[(MH)*4 + mq][(NH)*2 + nq], 0,0,0);\
  __builtin_amdgcn_s_setprio(0);

template <int NSEG>
__device__ __forceinline__ void gemm_pipe6(
    const unsigned short* __restrict__ A0p, const unsigned short* __restrict__ B0p,
    int lda0, int kt0,
    const unsigned short* __restrict__ A1p, const unsigned short* __restrict__ B1p,
    int lda1, int kt1,
    int arow0, int brow0,
    unsigned short (*lA)[2][8192], unsigned short (*lB)[2][8192],
    f32x4 acc[8][4]) {
  const int tid = threadIdx.x;
  const int lane = tid & 63, w = tid >> 6;
  const int wrow = w >> 2, wcol = w & 3;   // 2M x 4N wave grid, per-wave 128x64
  const int rl = lane & 15, s = lane >> 4;
  const int br = (wcol & 1) * 64;
  const int kt = (NSEG == 2) ? (kt0 + kt1) : kt0;

  // staging: thread covers chunk c1 (rows 0-63, "lower") and c2 (rows 64-127,
  // "upper") of each 128-row half
  const int c1 = tid, c2 = tid + 512;
  const int r1 = c1 >> 3, sl1 = (c1 & 7) ^ (r1 & 7);
  const int r2 = c2 >> 3, sl2 = (c2 & 7) ^ (r2 & 7);
  const unsigned short* gA0lo = A0p + (size_t)(arow0 + r1) * lda0 + sl1 * 8;
  const unsigned short* gA0hi = A0p + (size_t)(arow0 + r2) * lda0 + sl2 * 8;
  const unsigned short* gB0lo = B0p + (size_t)(brow0 + r1) * lda0 + sl1 * 8;
  const unsigned short* gB0hi = B0p + (size_t)(brow0 + r2) * lda0 + sl2 * 8;
  const unsigned short* gA1lo = gA0lo; const unsigned short* gA1hi = gA0hi;
  const unsigned short* gB1lo = gB0lo; const unsigned short* gB1hi = gB0hi;
  if (NSEG == 2) {
    gA1lo = A1p + (size_t)(arow0 + r1) * lda1 + sl1 * 8;
    gA1hi = A1p + (size_t)(arow0 + r2) * lda1 + sl2 * 8;
    gB1lo = B1p + (size_t)(brow0 + r1) * lda1 + sl1 * 8;
    gB1hi = B1p + (size_t)(brow0 + r2) * lda1 + sl2 * 8;
  }
  const size_t hs0 = (size_t)128 * lda0, hs1 = (size_t)128 * lda1;

  // stage one quarter-unit (2 loads: the same 64-row band of both halves)
  auto stgAlo = [&](int tt) {
    const unsigned short* p = gA0lo; size_t hs = hs0; int rel = tt;
    if (NSEG == 2 && tt >= kt0) { p = gA1lo; hs = hs1; rel = tt - kt0; }
    p += (size_t)rel * 64;
    GLOAD16(p,      &lA[tt & 1][0][(size_t)c1 * 8]);
    GLOAD16(p + hs, &lA[tt & 1][1][(size_t)c1 * 8]);
  };
  auto stgAhi = [&](int tt) {
    const unsigned short* p = gA0hi; size_t hs = hs0; int rel = tt;
    if (NSEG == 2 && tt >= kt0) { p = gA1hi; hs = hs1; rel = tt - kt0; }
    p += (size_t)rel * 64;
    GLOAD16(p,      &lA[tt & 1][0][(size_t)c2 * 8]);
    GLOAD16(p + hs, &lA[tt & 1][1][(size_t)c2 * 8]);
  };
  auto stgBlo = [&](int tt) {
    const unsigned short* p = gB0lo; size_t hs = hs0; int rel = tt;
    if (NSEG == 2 && tt >= kt0) { p = gB1lo; hs = hs1; rel = tt - kt0; }
    p += (size_t)rel * 64;
    GLOAD16(p,      &lB[tt & 1][0][(size_t)c1 * 8]);
    GLOAD16(p + hs, &lB[tt & 1][1][(size_t)c1 * 8]);
  };
  auto stgBhi = [&](int tt) {
    const unsigned short* p = gB0hi; size_t hs = hs0; int rel = tt;
    if (NSEG == 2 && tt >= kt0) { p = gB1hi; hs = hs1; rel = tt - kt0; }
    p += (size_t)rel * 64;
    GLOAD16(p,      &lB[tt & 1][0][(size_t)c2 * 8]);
    GLOAD16(p + hs, &lB[tt & 1][1][(size_t)c2 * 8]);
  };

  // prologue: tile 0 complete (8 loads, oldest), then tile 1 partial (6 loads)
  stgAlo(0); stgAhi(0); stgBlo(0); stgBhi(0);
  stgAlo(1); stgBlo(1); stgBhi(1);        // A-upper(1) comes at iter0 P0
  asm volatile("s_waitcnt vmcnt(6)" ::: "memory");   // tile 0 landed
  BAR();
  __builtin_amdgcn_sched_barrier(0);

#pragma unroll 2
  for (int t = 0; t < kt; ++t) {
    const unsigned short* Ac = &lA[t & 1][wrow][0];
    const unsigned short* Bc = &lB[t & 1][wcol >> 1][0];
    bf16x8 alo[4][2], ahi[4][2], blo[2][2], bhi[2][2];

    // ---- P0: read A-lo(8) + B-lo(4); stage A-upper(t+1); MFMA Q(0,0) ----
    READ_A4(alo, Ac, 0);
    READ_B2(blo, Bc, br);
    if (t + 1 < kt) stgAhi(t + 1);
    BAR(); LGKM0();
    MFMA_Q(0, 0, alo, blo);
    BAR();

    // ---- P1: read B-hi(4); stage A-lower(t+2); MFMA Q(0,1) ----
    READ_B2(bhi, Bc, br + 32);
    if (t + 2 < kt) stgAlo(t + 2);
    BAR(); LGKM0();
    MFMA_Q(0, 1, alo, bhi);
    BAR();

    // ---- P2: read A-hi(8); stage B-lower(t+2); MFMA Q(1,1) ----
    READ_A4(ahi, Ac, 64);
    if (t + 2 < kt) stgBlo(t + 2);
    BAR(); LGKM0();
    MFMA_Q(1, 1, ahi, bhi);
    BAR();

    // ---- P3: stage B-upper(t+2); MFMA Q(1,0); counted vmcnt(6) ----
    if (t + 2 < kt) stgBhi(t + 2);
    BAR();
    MFMA_Q(1, 0, ahi, blo);
    if (t + 2 < kt)      { asm volatile("s_waitcnt vmcnt(6)" ::: "memory"); }
    else if (t + 1 < kt) { asm volatile("s_waitcnt vmcnt(0)" ::: "memory"); }
    BAR();
  }
}

// u = bf16( svec[col] * (xc @ W_in + b_in) )
__global__ __launch_bounds__(512, 2) void gemm_u_kernel(
    const unsigned short* __restrict__ xc, const unsigned short* __restrict__ Wtin,
    const float* __restrict__ b_in, const float* __restrict__ svec,
    unsigned short* __restrict__ u) {
  __shared__ __align__(16) unsigned short lA[2][2][8192];
  __shared__ __align__(16) unsigned short lB[2][2][8192];
  f32x4 acc[8][4];
  const f32x4 z = {0.f, 0.f, 0.f, 0.f};
#pragma unroll
  for (int i = 0; i < 8; i++)
#pragma unroll
    for (int n = 0; n < 4; n++) acc[i][n] = z;

  int bid = blockIdx.x;
  int swz = (bid & 7) * 64 + (bid >> 3);   // 512 % 8 == 0: bijective
  int bcol = swz >> 7, brow = swz & 127;

  gemm_pipe6<1>(xc, Wtin, KC, KC / 64, xc, Wtin, KC, 0,
                brow * 256, bcol * 256, lA, lB, acc);

  const int lane = threadIdx.x & 63, w = threadIdx.x >> 6;
  const int wrow = w >> 2, wcol = w & 3;
  const int rl = lane & 15, s = lane >> 4;
  const int colb = bcol * 256 + wcol * 64 + rl;
  const int rowb = brow * 256 + wrow * 128 + s * 4;
#pragma unroll
  for (int n = 0; n < 4; n++) {
    int col = colb + n * 16;
    float bi = b_in[col], sv = svec[col];
#pragma unroll
    for (int i = 0; i < 8; i++) {
#pragma unroll
      for (int r = 0; r < 4; r++) {
        int row = rowb + i * 16 + r;
        u[(size_t)row * DHID + col] = f2bf((acc[i][n][r] + bi) * sv);
      }
    }
  }
}

// out = 0.5f * (xc @ W_dx + h @ W_out + b_dx + b_out)  (one merged 33-tile pipe)
__global__ __launch_bounds__(512, 2) void gemm_out_kernel(
    const unsigned short* __restrict__ xc, const unsigned short* __restrict__ Wtdx,
    const unsigned short* __restrict__ h, const unsigned short* __restrict__ Wtout,
    const float* __restrict__ b_dx, const float* __restrict__ b_out,
    float* __restrict__ out) {
  __shared__ __align__(16) unsigned short lA[2][2][8192];
  __shared__ __align__(16) unsigned short lB[2][2][8192];
  f32x4 acc[8][4];
  const f32x4 z = {0.f, 0.f, 0.f, 0.f};
#pragma unroll
  for (int i = 0; i < 8; i++)
#pragma unroll
    for (int n = 0; n < 4; n++) acc[i][n] = z;

  int bid = blockIdx.x;
  int swz = (bid & 7) * 64 + (bid >> 3);
  int bcol = swz >> 7, brow = swz & 127;

  gemm_pipe6<2>(xc, Wtdx, KC, KC / 64, h, Wtout, DHID, DHID / 64,
                brow * 256, bcol * 256, lA, lB, acc);

  const int lane = threadIdx.x & 63, w = threadIdx.x >> 6;
  const int wrow = w >> 2, wcol = w & 3;
  const int rl = lane & 15, s = lane >> 4;
  const int colb = bcol * 256 + wcol * 64 + rl;
  const int rowb = brow * 256 + wrow * 128 + s * 4;
#pragma unroll
  for (int n = 0; n < 4; n++) {
    int col = colb + n * 16;
    float bb = b_dx[col] + b_out[col];
#pragma unroll
    for (int i = 0; i < 8; i++) {
#pragma unroll
      for (int r = 0; r < 4; r++) {
        int row = rowb + i * 16 + r;
        out[(size_t)row * DOUT + col] = 0.5f * (acc[i][n][r] + bb);
      }
    }
  }
}

// ---------------- chunked scan: h_t = a h_{t-1} + u_t ----------------

__global__ __launch_bounds__(256) void scan1_kernel(
    const float* __restrict__ avec, unsigned short* __restrict__ uh,
    float* __restrict__ carry) {
  int b = blockIdx.x >> 5, c = blockIdx.x & 31;
  int d0 = threadIdx.x * 4;
  float4 a4 = *(const float4*)(avec + d0);
  unsigned short* p = uh + ((size_t)(b * S_DIM + c * LCHUNK)) * DHID + d0;
  float h0 = 0.f, h1 = 0.f, h2 = 0.f, h3 = 0.f;
#pragma unroll 4
  for (int t = 0; t < LCHUNK; t++) {
    u16x4 v = *(u16x4*)(p + (size_t)t * DHID);
    h0 = fmaf(a4.x, h0, bf2f(v.x));
    h1 = fmaf(a4.y, h1, bf2f(v.y));
    h2 = fmaf(a4.z, h2, bf2f(v.z));
    h3 = fmaf(a4.w, h3, bf2f(v.w));
    v.x = f2bf(h0); v.y = f2bf(h1); v.z = f2bf(h2); v.w = f2bf(h3);
    *(u16x4*)(p + (size_t)t * DHID) = v;
  }
  float4 cv = {h0, h1, h2, h3};
  *(float4*)(carry + ((size_t)b * NCHUNK + c) * DHID + d0) = cv;
}

__global__ __launch_bounds__(256) void scan2_kernel(
    const float* __restrict__ avec, const float* __restrict__ carry,
    float* __restrict__ Hprev) {
  int gid = blockIdx.x * 256 + threadIdx.x;  // 0..8191
  int b = gid >> 10, d = gid & 1023;
  float a = avec[d];
  float aL = a;
#pragma unroll
  for (int i = 0; i < 7; i++) aL *= aL;  // a^128
  float H = 0.f;
#pragma unroll
  for (int c = 0; c < NCHUNK; c++) {
    size_t idx = ((size_t)b * NCHUNK + c) * DHID + d;
    Hprev[idx] = H;
    H = aL * H + carry[idx];
  }
}

__global__ __launch_bounds__(256) void scan3_kernel(
    const float* __restrict__ avec, unsigned short* __restrict__ uh,
    const float* __restrict__ Hprev) {
  int b = blockIdx.x >> 5, c = blockIdx.x & 31;
  int d0 = threadIdx.x * 4;
  float4 Hp = *(const float4*)(Hprev + ((size_t)b * NCHUNK + c) * DHID + d0);
  if (Hp.x == 0.f && Hp.y == 0.f && Hp.z == 0.f && Hp.w == 0.f) return;  // c==0
  float4 a4 = *(const float4*)(avec + d0);
  float p0 = a4.x * Hp.x, p1 = a4.y * Hp.y, p2 = a4.z * Hp.z, p3 = a4.w * Hp.w;
  unsigned short* p = uh + ((size_t)(b * S_DIM + c * LCHUNK)) * DHID + d0;
#pragma unroll 4
  for (int t = 0; t < LCHUNK; t++) {
    u16x4 v = *(u16x4*)(p + (size_t)t * DHID);
    v.x = f2bf(bf2f(v.x) + p0);
    v.y = f2bf(bf2f(v.y) + p1);
    v.z = f2bf(bf2f(v.z) + p2);
    v.w = f2bf(bf2f(v.w) + p3);
    *(u16x4*)(p + (size_t)t * DHID) = v;
    p0 *= a4.x; p1 *= a4.y; p2 *= a4.z; p3 *= a4.w;
  }
}

// ---------------- launch ----------------

extern "C" void kernel_launch(void* const* d_in, const int* in_sizes, int n_in,
                              void* d_out, int out_size, void* d_ws, size_t ws_size,
                              hipStream_t stream) {
  const float* x       = (const float*)d_in[0];
  const float* a_logit = (const float*)d_in[1];
  const float* W_dx    = (const float*)d_in[2];
  const float* b_dx    = (const float*)d_in[3];
  const float* W_in    = (const float*)d_in[4];
  const float* b_in    = (const float*)d_in[5];
  const float* W_out   = (const float*)d_in[6];
  const float* b_out   = (const float*)d_in[7];
  float* out = (float*)d_out;

  char* ws = (char*)d_ws;
  size_t off = 0;
  auto alloc = [&](size_t bytes) {
    void* p = ws + off;
    off += (bytes + 255) & ~(size_t)255;
    return p;
  };
  unsigned short* xc    = (unsigned short*)alloc((size_t)MTOT * KC * 2);
  unsigned short* Wtdx  = (unsigned short*)alloc((size_t)DOUT * KC * 2);
  unsigned short* Wtin  = (unsigned short*)alloc((size_t)DHID * KC * 2);
  unsigned short* Wtout = (unsigned short*)alloc((size_t)DOUT * DHID * 2);
  unsigned short* uh    = (unsigned short*)alloc((size_t)MTOT * DHID * 2);
  float* carry = (float*)alloc((size_t)B_DIM * NCHUNK * DHID * 4);
  float* Hprev = (float*)alloc((size_t)B_DIM * NCHUNK * DHID * 4);
  float* avec  = (float*)alloc(DHID * 4);
  float* svec  = (float*)alloc(DHID * 4);
  (void)ws_size; (void)in_sizes; (void)n_in; (void)out_size;

  prep_a_kernel<<<4, 256, 0, stream>>>(a_logit, avec, svec);
  transpose_cast_kernel<<<dim3(KC / 32, 32), 256, 0, stream>>>(W_dx, Wtdx, KCAT, KC);
  transpose_cast_kernel<<<dim3(KC / 32, 32), 256, 0, stream>>>(W_in, Wtin, KCAT, KC);
  transpose_cast_kernel<<<dim3(32, 32), 256, 0, stream>>>(W_out, Wtout, DHID, DHID);
  build_xc_kernel<<<(MTOT * (KC / 4) + 255) / 256, 256, 0, stream>>>(x, xc);

  gemm_u_kernel<<<512, 512, 0, stream>>>(xc, Wtin, b_in, svec, uh);

  scan1_kernel<<<B_DIM * NCHUNK, 256, 0, stream>>>(avec, uh, carry);
  scan2_kernel<<<32, 256, 0, stream>>>(avec, carry, Hprev);
  scan3_kernel<<<B_DIM * NCHUNK, 256, 0, stream>>>(avec, uh, Hprev);

  gemm_out_kernel<<<512, 512, 0, stream>>>(xc, Wtdx, uh, Wtout, b_dx, b_out, out);
}